// Round 15
// baseline (671.787 us; speedup 1.0000x reference)
//
#include <hip/hip_runtime.h>
#include <math.h>

#define BB 64
#define CC 512
#define HW 784
#define DD 512
#define GR 512
#define KK 20

typedef __bf16 bf16x8 __attribute__((ext_vector_type(8)));
typedef float f32x16 __attribute__((ext_vector_type(16)));

__device__ inline unsigned short bf16rtn(float f) {
  unsigned int u = __builtin_bit_cast(unsigned int, f);
  unsigned int r = (u + 0x7FFFu + ((u >> 16) & 1u)) >> 16;
  return (unsigned short)r;
}

__device__ __forceinline__ float apply_act(float v, int act) {
  if (act == 1) return v > 0.f ? v : 0.f;
  if (act == 2) return 0.5f * v * (1.0f + erff(v * 0.70710678118654752f));
  if (act == 3) return 1.0f / (1.0f + expf(-v));
  return v;
}

// ---------------------------------------------------------------------------
// fused_A (R14 grid layout, 1236 blocks):
//   [0,64):      mlpA  — MLP stages 1-5 (x_embed -> x_main)
//   [64,1216):   gram (5/9) + u (4/9) interleave
//   [1216,1236): offs
// R15 change: u_body register-double-buffers its staging (prefetch chunk c+1
// into VGPRs while computing chunk c) — hides HBM latency under compute.
// ---------------------------------------------------------------------------
struct FAParams {
  const float* X; const float* Wg; const float* C; const float* gbias;
  const float* x_embed;
  const float* attn_w1; const float* attn_b1;
  const float* attn_w2; const float* attn_b2;
  const float* ln_ff_g; const float* ln_ff_b;
  const float* ff_w1; const float* ff_b1;
  const float* ff_w2; const float* ff_b2;
  float* G; float* U; float* offs; float* xm;
};

__device__ __forceinline__ void gram_body(int gid, const float* __restrict__ X,
                                          float* __restrict__ G,
                                          float* __restrict__ ldsf) {
  unsigned short* __restrict__ Apl = (unsigned short*)ldsf;
  unsigned short* __restrict__ Bpl = (unsigned short*)ldsf + 16384;
  const int b = gid / 10;
  int lin = gid % 10;
  int i = 0;
  while (lin >= 4 - i) { lin -= 4 - i; ++i; }
  const int j = i + lin;  // i <= j
  const bool diag = (i == j);

  const float* __restrict__ xb = X + (size_t)b * (CC * HW);
  const int tid = threadIdx.x;
  const int w = tid >> 6, l = tid & 63;
  const int wr = w >> 1;
  const int wc = w & 1;

  f32x16 acc0 = {};
  f32x16 acc1 = {};

  const int sr = tid >> 2;
  const int lane4 = tid & 3;

  for (int it = 0; it < 7; ++it) {
    const int k0 = it * 112;
    __syncthreads();
#pragma unroll
    for (int q = 0; q < 7; ++q) {
      const int pos = lane4 + q * 4;
      const int chunk = pos >> 1;
      const int soff =
          sr * 128 + (((chunk ^ (sr & 7)) << 3) | ((pos & 1) << 2));
#pragma unroll
      for (int pnl = 0; pnl < 2; ++pnl) {
        if (pnl && diag) break;
        const int rowbase = (pnl ? j : i) * 128;
        float4 v =
            *(const float4*)(xb + (size_t)(rowbase + sr) * HW + k0 + pos * 4);
        unsigned int p0 = bf16rtn(v.x) | ((unsigned int)bf16rtn(v.y) << 16);
        unsigned int p1 = bf16rtn(v.z) | ((unsigned int)bf16rtn(v.w) << 16);
        *(uint2*)((pnl ? Bpl : Apl) + soff) = make_uint2(p0, p1);
      }
    }
    __syncthreads();
    const unsigned short* __restrict__ bP = diag ? Apl : Bpl;
#pragma unroll
    for (int ks = 0; ks < 7; ++ks) {
      const int chunk = ks * 2 + (l >> 5);
      const int ar = wr * 32 + (l & 31);
      bf16x8 a = *(const bf16x8*)(Apl + ar * 128 + ((chunk ^ (ar & 7)) << 3));
      const int br0 = wc * 64 + (l & 31);
      const int br1 = br0 + 32;
      bf16x8 b0 = *(const bf16x8*)(bP + br0 * 128 + ((chunk ^ (br0 & 7)) << 3));
      bf16x8 b1 = *(const bf16x8*)(bP + br1 * 128 + ((chunk ^ (br1 & 7)) << 3));
      acc0 = __builtin_amdgcn_mfma_f32_32x32x16_bf16(a, b0, acc0, 0, 0, 0);
      acc1 = __builtin_amdgcn_mfma_f32_32x32x16_bf16(a, b1, acc1, 0, 0, 0);
    }
  }

  const float sc = 1.0f / (float)HW;
  float* __restrict__ gb = G + (size_t)b * (CC * CC);
  const int rowbase = i * 128 + wr * 32 + 4 * (l >> 5);
  const int colbase = j * 128 + wc * 64 + (l & 31);
#pragma unroll
  for (int n = 0; n < 2; ++n) {
    const f32x16 a = n ? acc1 : acc0;
#pragma unroll
    for (int reg = 0; reg < 16; ++reg) {
      const int row = rowbase + (reg & 3) + 8 * (reg >> 2);
      const int col = colbase + n * 32;
      gb[(size_t)row * CC + col] = a[reg] * sc;
    }
  }
  if (!diag) {
    // mirror store via LDS transpose (coalesced float4 writes)
    float* __restrict__ T = ldsf;
    __syncthreads();
    const int rl0 = wr * 32 + 4 * (l >> 5);
    const int cl0 = wc * 64 + (l & 31);
#pragma unroll
    for (int n = 0; n < 2; ++n) {
      const f32x16 a = n ? acc1 : acc0;
      const int c_local = cl0 + n * 32;
      const int s = (c_local & 31) << 2;
#pragma unroll
      for (int reg = 0; reg < 16; ++reg) {
        const int r_local = rl0 + (reg & 3) + 8 * (reg >> 2);
        T[c_local * 128 + (r_local ^ s)] = a[reg] * sc;
      }
    }
    __syncthreads();
#pragma unroll
    for (int q = 0; q < 8; ++q) {
      const int slot = q * 512 + tid;
      const int cc = slot >> 5;
      const int rq4 = (slot & 31) * 4;
      const int s = (cc & 31) << 2;
      float4 v = *(const float4*)&T[cc * 128 + (rq4 ^ s)];
      *(float4*)(gb + (size_t)(j * 128 + cc) * CC + i * 128 + rq4) = v;
    }
  }
}

// u: 512 rows, register double-buffered staging; math identical to R14.
__device__ __forceinline__ void u_body(int uid, const float* __restrict__ W,
                                       const float* __restrict__ C,
                                       float* __restrict__ U,
                                       float* __restrict__ Ws /*[512][36]*/,
                                       float* __restrict__ Ct /*[20][36]*/) {
  const int tid = threadIdx.x;
  const int rt = tid >> 2, kq = tid & 3;
  const int srow = tid >> 3;        // 0..63
  const int scol = (tid & 7) * 4;   // 0..28
  const size_t row0 = (size_t)uid << 9;

  float acc[4][5] = {};
  float4 wreg[8];
  float4 creg = make_float4(0.f, 0.f, 0.f, 0.f);

  // prologue: chunk 0 -> regs
#pragma unroll
  for (int q = 0; q < 8; ++q)
    wreg[q] = *(const float4*)(W + (row0 + q * 64 + srow) * GR + scol);
  if (tid < 160) creg = *(const float4*)(C + (size_t)(tid >> 3) * GR + scol);

  for (int c = 0; c < 16; ++c) {
    __syncthreads();  // prev compute done -> LDS reusable
#pragma unroll
    for (int q = 0; q < 8; ++q)
      *(float4*)&Ws[(q * 64 + srow) * 36 + scol] = wreg[q];
    if (tid < 160) *(float4*)&Ct[(tid >> 3) * 36 + scol] = creg;
    if (c < 15) {
      const int k0n = (c + 1) * 32;
#pragma unroll
      for (int q = 0; q < 8; ++q)
        wreg[q] =
            *(const float4*)(W + (row0 + q * 64 + srow) * GR + k0n + scol);
      if (tid < 160)
        creg = *(const float4*)(C + (size_t)(tid >> 3) * GR + k0n + scol);
    }
    __syncthreads();
#pragma unroll
    for (int kk4 = 0; kk4 < 8; ++kk4) {
      float4 wv[4];
#pragma unroll
      for (int u = 0; u < 4; ++u)
        wv[u] = *(const float4*)&Ws[(rt + u * 128) * 36 + kk4 * 4];
#pragma unroll
      for (int q = 0; q < 5; ++q) {
        float4 c4 = *(const float4*)&Ct[(kq * 5 + q) * 36 + kk4 * 4];
#pragma unroll
        for (int u = 0; u < 4; ++u) {
          acc[u][q] = fmaf(wv[u].x, c4.x, acc[u][q]);
          acc[u][q] = fmaf(wv[u].y, c4.y, acc[u][q]);
          acc[u][q] = fmaf(wv[u].z, c4.z, acc[u][q]);
          acc[u][q] = fmaf(wv[u].w, c4.w, acc[u][q]);
        }
      }
    }
  }
#pragma unroll
  for (int u = 0; u < 4; ++u)
#pragma unroll
    for (int q = 0; q < 5; ++q)
      U[(row0 + rt + u * 128) * KK + kq * 5 + q] = acc[u][q];
}

template <int ACT, bool GATE, bool RES>
__device__ __forceinline__ void gemv_1c(const float* __restrict__ x,
                                        const float* __restrict__ W,
                                        const float* __restrict__ bias,
                                        const float* __restrict__ gate,
                                        const float* __restrict__ res,
                                        float* __restrict__ y, int K, int N) {
  const int col = threadIdx.x;
  float a0 = 0.f, a1 = 0.f, a2 = 0.f, a3 = 0.f;
  const float* __restrict__ Wp = W + col;
#pragma unroll 8
  for (int k = 0; k < K; k += 4) {
    a0 = fmaf(x[k + 0], Wp[(size_t)(k + 0) * N], a0);
    a1 = fmaf(x[k + 1], Wp[(size_t)(k + 1) * N], a1);
    a2 = fmaf(x[k + 2], Wp[(size_t)(k + 2) * N], a2);
    a3 = fmaf(x[k + 3], Wp[(size_t)(k + 3) * N], a3);
  }
  float s = apply_act((a0 + a1) + (a2 + a3) + bias[col], ACT);
  if (GATE) s *= gate[col];
  if (RES) s += res[col];
  y[col] = s;
  __syncthreads();
}

__device__ __forceinline__ void ln512t(const float* __restrict__ y,
                                       const float* __restrict__ g,
                                       const float* __restrict__ bt,
                                       float* __restrict__ o,
                                       float* __restrict__ red) {
  const int tid = threadIdx.x;
  const float v = y[tid];
  float s = v, ss = v * v;
#pragma unroll
  for (int of = 32; of; of >>= 1) {
    s += __shfl_xor(s, of);
    ss += __shfl_xor(ss, of);
  }
  const int w = tid >> 6;
  if ((tid & 63) == 0) { red[w * 2] = s; red[w * 2 + 1] = ss; }
  __syncthreads();
  s = 0.f; ss = 0.f;
#pragma unroll
  for (int q = 0; q < 8; ++q) { s += red[q * 2]; ss += red[q * 2 + 1]; }
  const float m = s * (1.0f / 512.0f);
  const float inv = rsqrtf(ss * (1.0f / 512.0f) - m * m + 1e-5f);
  o[tid] = (v - m) * inv * g[tid] + bt[tid];
  __syncthreads();
}

__device__ __forceinline__ void mlpA_body(int b, const FAParams& p,
                                          float* __restrict__ lds) {
  float* xe = lds;
  float* h1 = lds + 512;
  float* xa = lds + 1024;
  float* xt = lds + 1536;
  float* f1 = lds + 2048;
  float* red = lds + 4096;
  const int tid = threadIdx.x;

  xe[tid] = p.x_embed[(size_t)b * 512 + tid];
  __syncthreads();
  gemv_1c<1, false, false>(xe, p.attn_w1, p.attn_b1, nullptr, nullptr, h1, 512,
                           512);
  gemv_1c<3, true, false>(h1, p.attn_w2, p.attn_b2, xe, nullptr, xa, 512, 512);
  ln512t(xa, p.ln_ff_g, p.ln_ff_b, xt, red);
  {
    float a[4] = {0.f, 0.f, 0.f, 0.f};
    for (int k = 0; k < 512; ++k) {
      const float xv = xt[k];
      const float* __restrict__ Wr = p.ff_w1 + (size_t)k * 2048;
      a[0] = fmaf(xv, Wr[tid], a[0]);
      a[1] = fmaf(xv, Wr[tid + 512], a[1]);
      a[2] = fmaf(xv, Wr[tid + 1024], a[2]);
      a[3] = fmaf(xv, Wr[tid + 1536], a[3]);
    }
#pragma unroll
    for (int q = 0; q < 4; ++q)
      f1[tid + q * 512] = apply_act(a[q] + p.ff_b1[tid + q * 512], 2);
    __syncthreads();
  }
  {
    const int col = tid;
    float a0 = 0.f, a1 = 0.f, a2 = 0.f, a3 = 0.f;
    const float* __restrict__ Wp = p.ff_w2 + col;
#pragma unroll 8
    for (int k = 0; k < 2048; k += 4) {
      a0 = fmaf(f1[k + 0], Wp[(size_t)(k + 0) * 512], a0);
      a1 = fmaf(f1[k + 1], Wp[(size_t)(k + 1) * 512], a1);
      a2 = fmaf(f1[k + 2], Wp[(size_t)(k + 2) * 512], a2);
      a3 = fmaf(f1[k + 3], Wp[(size_t)(k + 3) * 512], a3);
    }
    p.xm[(size_t)b * 512 + col] =
        (a0 + a1) + (a2 + a3) + p.ff_b2[col] + xa[col];
  }
}

__global__ __launch_bounds__(512, 4) void fused_A(FAParams p) {
  extern __shared__ float ldsf[];
  const int bid = blockIdx.x;
  if (bid < 64) {
    mlpA_body(bid, p, ldsf);
  } else if (bid < 1216) {
    const int g = (bid - 64) / 9, r = (bid - 64) % 9;
    if (r < 5) {
      gram_body(g * 5 + r, p.X, p.G, ldsf);
    } else {
      u_body(g * 4 + (r - 5), p.Wg, p.C, p.U, ldsf, ldsf + 512 * 36);
    }
  } else {
    const int k = bid - 1216, t = threadIdx.x;
    if (t < 64) {
      float a = 0.f;
      for (int r2 = t; r2 < GR; r2 += 64) {
        float c = p.C[k * GR + r2];
        a += c * c - 2.0f * p.gbias[r2] * c;
      }
#pragma unroll
      for (int o = 32; o; o >>= 1) a += __shfl_down(a, o);
      if (t == 0) p.offs[k] = a;
    }
  }
}

// ---------------------------------------------------------------------------
// scores (verbatim)
// ---------------------------------------------------------------------------
__global__ __launch_bounds__(128) void scores_k(const float* __restrict__ G,
                                                const float* __restrict__ U,
                                                float* __restrict__ P) {
  __shared__ float Gs[64][68];
  __shared__ float Ut[20][68];

  const int tid = threadIdx.x;
  const int bsub = tid & 31, kg = tid >> 5;
  const size_t s0 = (size_t)blockIdx.x << 9;

  float acc[2][5] = {};

  for (int c0 = 0; c0 < 512; c0 += 64) {
    __syncthreads();
#pragma unroll
    for (int q = 0; q < 8; ++q) {
      int bb = q * 8 + (tid >> 4);
      float4 g4 = *(const float4*)(G + (size_t)bb * (CC * CC) + s0 + c0 +
                                   (tid & 15) * 4);
      *(float4*)&Gs[bb][(tid & 15) * 4] = g4;
    }
#pragma unroll
    for (int e = 0; e < 10; ++e) {
      int f = e * 128 + tid;
      float val = U[(s0 + c0) * KK + f];
      Ut[f % 20][f / 20] = val;
    }
    __syncthreads();
#pragma unroll
    for (int kk4 = 0; kk4 < 16; ++kk4) {
      float4 ga = *(const float4*)&Gs[bsub][kk4 * 4];
      float4 gb2 = *(const float4*)&Gs[bsub + 32][kk4 * 4];
#pragma unroll
      for (int q = 0; q < 5; ++q) {
        float4 c4 = *(const float4*)&Ut[kg * 5 + q][kk4 * 4];
        acc[0][q] = fmaf(ga.x, c4.x, acc[0][q]);
        acc[0][q] = fmaf(ga.y, c4.y, acc[0][q]);
        acc[0][q] = fmaf(ga.z, c4.z, acc[0][q]);
        acc[0][q] = fmaf(ga.w, c4.w, acc[0][q]);
        acc[1][q] = fmaf(gb2.x, c4.x, acc[1][q]);
        acc[1][q] = fmaf(gb2.y, c4.y, acc[1][q]);
        acc[1][q] = fmaf(gb2.z, c4.z, acc[1][q]);
        acc[1][q] = fmaf(gb2.w, c4.w, acc[1][q]);
      }
    }
  }
#pragma unroll
  for (int q = 0; q < 5; ++q) {
    P[(size_t)blockIdx.x * 1280 + (kg * 5 + q) * 64 + bsub] = acc[0][q];
    P[(size_t)blockIdx.x * 1280 + (kg * 5 + q) * 64 + bsub + 32] = acc[1][q];
  }
}

// ---------------------------------------------------------------------------
// mlp_row v3 (verbatim R12/R14)
// ---------------------------------------------------------------------------
struct MlpRowParams {
  const float* xm;
  const float* centers;
  const float* gm_w; const float* gm_b;
  const float* ln1_g; const float* ln1_b;
  const float* m1_w; const float* m1_b;
  const float* m2_w1; const float* m2_b1;
  const float* m2_w2; const float* m2_b2;
  const float* out_w; const float* out_b;
  const float* P; const float* offs;
  float* out;
};

template <int ACT, bool GATE, bool RES, int KS>
__device__ __forceinline__ void gemv_ks(const float* __restrict__ x,
                                        const float* __restrict__ W,
                                        const float* __restrict__ bias,
                                        const float* __restrict__ gate,
                                        const float* __restrict__ res,
                                        float* __restrict__ y, int K,
                                        float* __restrict__ part) {
  constexpr int N = 1024 / KS;
  const int tid = threadIdx.x;
  const int col = tid & (N - 1);
  const int kg = tid / N;
  const int kper = K / KS;
  const int k0 = kg * kper;
  float a0 = 0.f, a1 = 0.f, a2 = 0.f, a3 = 0.f;
  const float* __restrict__ Wp = W + (size_t)k0 * N + col;
  const float* __restrict__ xp = x + k0;
#pragma unroll 8
  for (int k = 0; k < kper; k += 4) {
    a0 = fmaf(xp[k + 0], Wp[(size_t)(k + 0) * N], a0);
    a1 = fmaf(xp[k + 1], Wp[(size_t)(k + 1) * N], a1);
    a2 = fmaf(xp[k + 2], Wp[(size_t)(k + 2) * N], a2);
    a3 = fmaf(xp[k + 3], Wp[(size_t)(k + 3) * N], a3);
  }
  part[tid] = (a0 + a1) + (a2 + a3);
  __syncthreads();
  if (tid < N) {
    float s = part[tid];
#pragma unroll
    for (int q = 1; q < KS; ++q) s += part[q * N + tid];
    s = apply_act(s + bias[tid], ACT);
    if (GATE) s *= gate[tid];
    if (RES) s += res[tid];
    y[tid] = s;
  }
  __syncthreads();
}

__device__ __forceinline__ void ln512g(const float* __restrict__ y,
                                       const float* __restrict__ g,
                                       const float* __restrict__ bt,
                                       float* __restrict__ o,
                                       float* __restrict__ red) {
  const int tid = threadIdx.x;
  if (tid < 512) {
    const float v = y[tid];
    float s = v, ss = v * v;
#pragma unroll
    for (int of = 32; of; of >>= 1) {
      s += __shfl_xor(s, of);
      ss += __shfl_xor(ss, of);
    }
    const int w = tid >> 6;
    if ((tid & 63) == 0) { red[w * 2] = s; red[w * 2 + 1] = ss; }
  }
  __syncthreads();
  if (tid < 512) {
    float s = 0.f, ss = 0.f;
#pragma unroll
    for (int q = 0; q < 8; ++q) { s += red[q * 2]; ss += red[q * 2 + 1]; }
    const float m = s * (1.0f / 512.0f);
    const float inv = rsqrtf(ss * (1.0f / 512.0f) - m * m + 1e-5f);
    o[tid] = (y[tid] - m) * inv * g[tid] + bt[tid];
  }
  __syncthreads();
}

__global__ __launch_bounds__(1024) void mlp_row(MlpRowParams p) {
  __shared__ float xt[512], xf[1024], xh[512], hh[512], h2[512], h3[256];
  __shared__ float part[1024];
  __shared__ float red[16];
  __shared__ float ps[32][20];
  __shared__ float vals[20];
  __shared__ int bestIdx;

  const int b = blockIdx.x;
  const int tid = threadIdx.x;

  {
    const int g = tid >> 5, k = tid & 31;
    if (k < 20) {
      float s = 0.f;
#pragma unroll 4
      for (int m2 = 0; m2 < 16; ++m2)
        s += p.P[(size_t)(g + 32 * m2) * 1280 + k * 64 + b];
      ps[g][k] = s;
    }
    __syncthreads();
    if (tid < 20) {
      float s = 0.f;
#pragma unroll
      for (int q = 0; q < 32; ++q) s += ps[q][tid];
      vals[tid] = p.offs[tid] - 2.0f * s;
    }
    __syncthreads();
    if (tid == 0) {
      float best = vals[0];
      int bi = 0;
      for (int k2 = 1; k2 < 20; ++k2)
        if (vals[k2] < best) { best = vals[k2]; bi = k2; }
      bestIdx = bi;
    }
    __syncthreads();
    if (tid < 512) {
      xf[tid] = p.xm[(size_t)b * 512 + tid];
      xf[512 + tid] = p.centers[(size_t)bestIdx * 512 + tid];
    }
    __syncthreads();
  }

  gemv_ks<2, false, false, 2>(xf, p.gm_w, p.gm_b, nullptr, nullptr, xh, 1024,
                              part);
  ln512g(xh, p.ln1_g, p.ln1_b, xt, red);
  gemv_ks<2, false, true, 2>(xt, p.m1_w, p.m1_b, nullptr, xh, hh, 512, part);
  gemv_ks<2, false, false, 2>(hh, p.m2_w1, p.m2_b1, nullptr, nullptr, h2, 512,
                              part);
  gemv_ks<2, false, false, 4>(h2, p.m2_w2, p.m2_b2, nullptr, nullptr, h3, 512,
                              part);
  if (tid < 10) {
    float s = p.out_b[tid];
#pragma unroll 4
    for (int k = 0; k < 256; ++k) s = fmaf(h3[k], p.out_w[k * 10 + tid], s);
    p.out[(size_t)b * 10 + tid] = s;
  }
}

// ---------------------------------------------------------------------------
extern "C" void kernel_launch(void* const* d_in, const int* in_sizes, int n_in,
                              void* d_out, int out_size, void* d_ws,
                              size_t ws_size, hipStream_t stream) {
  const float* x_embed = (const float*)d_in[0];
  const float* x_image = (const float*)d_in[1];
  const float* attn_w1 = (const float*)d_in[2];
  const float* attn_b1 = (const float*)d_in[3];
  const float* attn_w2 = (const float*)d_in[4];
  const float* attn_b2 = (const float*)d_in[5];
  const float* ln_ff_g = (const float*)d_in[6];
  const float* ln_ff_b = (const float*)d_in[7];
  const float* ff_w1 = (const float*)d_in[8];
  const float* ff_b1 = (const float*)d_in[9];
  const float* ff_w2 = (const float*)d_in[10];
  const float* ff_b2 = (const float*)d_in[11];
  const float* gram_w = (const float*)d_in[12];
  const float* gram_b = (const float*)d_in[13];
  const float* centers = (const float*)d_in[14];
  const float* gm_w = (const float*)d_in[15];
  const float* gm_b = (const float*)d_in[16];
  const float* ln1_g = (const float*)d_in[17];
  const float* ln1_b = (const float*)d_in[18];
  const float* m1_w = (const float*)d_in[19];
  const float* m1_b = (const float*)d_in[20];
  const float* m2_w1 = (const float*)d_in[21];
  const float* m2_b1 = (const float*)d_in[22];
  const float* m2_w2 = (const float*)d_in[23];
  const float* m2_b2 = (const float*)d_in[24];
  const float* out_w = (const float*)d_in[25];
  const float* out_b = (const float*)d_in[26];

  float* ws = (float*)d_ws;
  size_t off = 0;
  auto alloc = [&](size_t nelem) {
    float* p = ws + off;
    off += (nelem + 63) & ~(size_t)63;
    return p;
  };
  float* G = alloc((size_t)BB * CC * CC);   // 67 MB
  float* U = alloc((size_t)CC * CC * KK);   // 21 MB
  float* P = alloc((size_t)512 * 1280);     // 2.6 MB
  float* offs = alloc(64);
  float* xm = alloc(BB * DD);

  hipFuncSetAttribute(reinterpret_cast<const void*>(fused_A),
                      hipFuncAttributeMaxDynamicSharedMemorySize, 76800);

  FAParams fp;
  fp.X = x_image; fp.Wg = gram_w; fp.C = centers; fp.gbias = gram_b;
  fp.x_embed = x_embed;
  fp.attn_w1 = attn_w1; fp.attn_b1 = attn_b1;
  fp.attn_w2 = attn_w2; fp.attn_b2 = attn_b2;
  fp.ln_ff_g = ln_ff_g; fp.ln_ff_b = ln_ff_b;
  fp.ff_w1 = ff_w1; fp.ff_b1 = ff_b1;
  fp.ff_w2 = ff_w2; fp.ff_b2 = ff_b2;
  fp.G = G; fp.U = U; fp.offs = offs; fp.xm = xm;

  MlpRowParams mp;
  mp.xm = xm;
  mp.centers = centers;
  mp.gm_w = gm_w; mp.gm_b = gm_b;
  mp.ln1_g = ln1_g; mp.ln1_b = ln1_b;
  mp.m1_w = m1_w; mp.m1_b = m1_b;
  mp.m2_w1 = m2_w1; mp.m2_b1 = m2_b1;
  mp.m2_w2 = m2_w2; mp.m2_b2 = m2_b2;
  mp.out_w = out_w; mp.out_b = out_b;
  mp.P = P; mp.offs = offs;
  mp.out = (float*)d_out;

  fused_A<<<1236, 512, 76800, stream>>>(fp);
  scores_k<<<512, 128, 0, stream>>>(G, U, P);
  mlp_row<<<64, 1024, 0, stream>>>(mp);
}

// Round 16
// 429.616 us; speedup vs baseline: 1.5637x; 1.5637x over previous
//
#include <hip/hip_runtime.h>
#include <math.h>

#define BB 64
#define CC 512
#define HW 784
#define DD 512
#define GR 512
#define KK 20

typedef __bf16 bf16x8 __attribute__((ext_vector_type(8)));
typedef float f32x16 __attribute__((ext_vector_type(16)));

__device__ inline unsigned short bf16rtn(float f) {
  unsigned int u = __builtin_bit_cast(unsigned int, f);
  unsigned int r = (u + 0x7FFFu + ((u >> 16) & 1u)) >> 16;
  return (unsigned short)r;
}

__device__ __forceinline__ float apply_act(float v, int act) {
  if (act == 1) return v > 0.f ? v : 0.f;
  if (act == 2) return 0.5f * v * (1.0f + erff(v * 0.70710678118654752f));
  if (act == 3) return 1.0f / (1.0f + expf(-v));
  return v;
}

// ---------------------------------------------------------------------------
// fused_A (R14 grid layout, 1236 blocks):
//   [0,64):      mlpA  — MLP stages 1-5 (x_embed -> x_main)
//   [64,1216):   gram (5/9) + u (4/9) interleave
//   [1216,1236): offs
// R16 change: gram slots get a bijective permutation so that all 10 tile-pair
// blocks of one batch land on one XCD (slot XCD = (g+r)&7 under round-robin
// dispatch) -> X panels L2-resident across their 4x re-reads.
// ---------------------------------------------------------------------------
struct FAParams {
  const float* X; const float* Wg; const float* C; const float* gbias;
  const float* x_embed;
  const float* attn_w1; const float* attn_b1;
  const float* attn_w2; const float* attn_b2;
  const float* ln_ff_g; const float* ln_ff_b;
  const float* ff_w1; const float* ff_b1;
  const float* ff_w2; const float* ff_b2;
  float* G; float* U; float* offs; float* xm;
};

__device__ __forceinline__ void gram_body(int gid, const float* __restrict__ X,
                                          float* __restrict__ G,
                                          float* __restrict__ ldsf) {
  unsigned short* __restrict__ Apl = (unsigned short*)ldsf;
  unsigned short* __restrict__ Bpl = (unsigned short*)ldsf + 16384;
  const int b = gid / 10;
  int lin = gid % 10;
  int i = 0;
  while (lin >= 4 - i) { lin -= 4 - i; ++i; }
  const int j = i + lin;  // i <= j
  const bool diag = (i == j);

  const float* __restrict__ xb = X + (size_t)b * (CC * HW);
  const int tid = threadIdx.x;
  const int w = tid >> 6, l = tid & 63;
  const int wr = w >> 1;
  const int wc = w & 1;

  f32x16 acc0 = {};
  f32x16 acc1 = {};

  const int sr = tid >> 2;
  const int lane4 = tid & 3;

  for (int it = 0; it < 7; ++it) {
    const int k0 = it * 112;
    __syncthreads();
#pragma unroll
    for (int q = 0; q < 7; ++q) {
      const int pos = lane4 + q * 4;
      const int chunk = pos >> 1;
      const int soff =
          sr * 128 + (((chunk ^ (sr & 7)) << 3) | ((pos & 1) << 2));
#pragma unroll
      for (int pnl = 0; pnl < 2; ++pnl) {
        if (pnl && diag) break;
        const int rowbase = (pnl ? j : i) * 128;
        float4 v =
            *(const float4*)(xb + (size_t)(rowbase + sr) * HW + k0 + pos * 4);
        unsigned int p0 = bf16rtn(v.x) | ((unsigned int)bf16rtn(v.y) << 16);
        unsigned int p1 = bf16rtn(v.z) | ((unsigned int)bf16rtn(v.w) << 16);
        *(uint2*)((pnl ? Bpl : Apl) + soff) = make_uint2(p0, p1);
      }
    }
    __syncthreads();
    const unsigned short* __restrict__ bP = diag ? Apl : Bpl;
#pragma unroll
    for (int ks = 0; ks < 7; ++ks) {
      const int chunk = ks * 2 + (l >> 5);
      const int ar = wr * 32 + (l & 31);
      bf16x8 a = *(const bf16x8*)(Apl + ar * 128 + ((chunk ^ (ar & 7)) << 3));
      const int br0 = wc * 64 + (l & 31);
      const int br1 = br0 + 32;
      bf16x8 b0 = *(const bf16x8*)(bP + br0 * 128 + ((chunk ^ (br0 & 7)) << 3));
      bf16x8 b1 = *(const bf16x8*)(bP + br1 * 128 + ((chunk ^ (br1 & 7)) << 3));
      acc0 = __builtin_amdgcn_mfma_f32_32x32x16_bf16(a, b0, acc0, 0, 0, 0);
      acc1 = __builtin_amdgcn_mfma_f32_32x32x16_bf16(a, b1, acc1, 0, 0, 0);
    }
  }

  const float sc = 1.0f / (float)HW;
  float* __restrict__ gb = G + (size_t)b * (CC * CC);
  const int rowbase = i * 128 + wr * 32 + 4 * (l >> 5);
  const int colbase = j * 128 + wc * 64 + (l & 31);
#pragma unroll
  for (int n = 0; n < 2; ++n) {
    const f32x16 a = n ? acc1 : acc0;
#pragma unroll
    for (int reg = 0; reg < 16; ++reg) {
      const int row = rowbase + (reg & 3) + 8 * (reg >> 2);
      const int col = colbase + n * 32;
      gb[(size_t)row * CC + col] = a[reg] * sc;
    }
  }
  if (!diag) {
    // mirror store via LDS transpose (coalesced float4 writes)
    float* __restrict__ T = ldsf;
    __syncthreads();
    const int rl0 = wr * 32 + 4 * (l >> 5);
    const int cl0 = wc * 64 + (l & 31);
#pragma unroll
    for (int n = 0; n < 2; ++n) {
      const f32x16 a = n ? acc1 : acc0;
      const int c_local = cl0 + n * 32;
      const int s = (c_local & 31) << 2;
#pragma unroll
      for (int reg = 0; reg < 16; ++reg) {
        const int r_local = rl0 + (reg & 3) + 8 * (reg >> 2);
        T[c_local * 128 + (r_local ^ s)] = a[reg] * sc;
      }
    }
    __syncthreads();
#pragma unroll
    for (int q = 0; q < 8; ++q) {
      const int slot = q * 512 + tid;
      const int cc = slot >> 5;
      const int rq4 = (slot & 31) * 4;
      const int s = (cc & 31) << 2;
      float4 v = *(const float4*)&T[cc * 128 + (rq4 ^ s)];
      *(float4*)(gb + (size_t)(j * 128 + cc) * CC + i * 128 + rq4) = v;
    }
  }
}

// u: R14 form (simple staged, no prefetch — R15's prefetch regressed).
__device__ __forceinline__ void u_body(int uid, const float* __restrict__ W,
                                       const float* __restrict__ C,
                                       float* __restrict__ U,
                                       float* __restrict__ Ws /*[512][36]*/,
                                       float* __restrict__ Ct /*[20][36]*/) {
  const int tid = threadIdx.x;
  const int rt = tid >> 2, kq = tid & 3;
  const size_t row0 = (size_t)uid << 9;

  float acc[4][5] = {};

  for (int k0 = 0; k0 < GR; k0 += 32) {
    __syncthreads();
#pragma unroll
    for (int q = 0; q < 8; ++q) {
      const int row = q * 64 + (tid >> 3);
      const int col = (tid & 7) * 4;
      float4 w4 = *(const float4*)(W + (row0 + row) * GR + k0 + col);
      *(float4*)&Ws[row * 36 + col] = w4;
    }
    if (tid < 160) {
      const int k = tid >> 3, pp = tid & 7;
      *(float4*)&Ct[k * 36 + pp * 4] = *(const float4*)(C + k * GR + k0 + pp * 4);
    }
    __syncthreads();
#pragma unroll
    for (int kk4 = 0; kk4 < 8; ++kk4) {
      float4 wv[4];
#pragma unroll
      for (int u = 0; u < 4; ++u)
        wv[u] = *(const float4*)&Ws[(rt + u * 128) * 36 + kk4 * 4];
#pragma unroll
      for (int q = 0; q < 5; ++q) {
        float4 c4 = *(const float4*)&Ct[(kq * 5 + q) * 36 + kk4 * 4];
#pragma unroll
        for (int u = 0; u < 4; ++u) {
          acc[u][q] = fmaf(wv[u].x, c4.x, acc[u][q]);
          acc[u][q] = fmaf(wv[u].y, c4.y, acc[u][q]);
          acc[u][q] = fmaf(wv[u].z, c4.z, acc[u][q]);
          acc[u][q] = fmaf(wv[u].w, c4.w, acc[u][q]);
        }
      }
    }
  }
#pragma unroll
  for (int u = 0; u < 4; ++u)
#pragma unroll
    for (int q = 0; q < 5; ++q)
      U[(row0 + rt + u * 128) * KK + kq * 5 + q] = acc[u][q];
}

template <int ACT, bool GATE, bool RES>
__device__ __forceinline__ void gemv_1c(const float* __restrict__ x,
                                        const float* __restrict__ W,
                                        const float* __restrict__ bias,
                                        const float* __restrict__ gate,
                                        const float* __restrict__ res,
                                        float* __restrict__ y, int K, int N) {
  const int col = threadIdx.x;
  float a0 = 0.f, a1 = 0.f, a2 = 0.f, a3 = 0.f;
  const float* __restrict__ Wp = W + col;
#pragma unroll 8
  for (int k = 0; k < K; k += 4) {
    a0 = fmaf(x[k + 0], Wp[(size_t)(k + 0) * N], a0);
    a1 = fmaf(x[k + 1], Wp[(size_t)(k + 1) * N], a1);
    a2 = fmaf(x[k + 2], Wp[(size_t)(k + 2) * N], a2);
    a3 = fmaf(x[k + 3], Wp[(size_t)(k + 3) * N], a3);
  }
  float s = apply_act((a0 + a1) + (a2 + a3) + bias[col], ACT);
  if (GATE) s *= gate[col];
  if (RES) s += res[col];
  y[col] = s;
  __syncthreads();
}

__device__ __forceinline__ void ln512t(const float* __restrict__ y,
                                       const float* __restrict__ g,
                                       const float* __restrict__ bt,
                                       float* __restrict__ o,
                                       float* __restrict__ red) {
  const int tid = threadIdx.x;
  const float v = y[tid];
  float s = v, ss = v * v;
#pragma unroll
  for (int of = 32; of; of >>= 1) {
    s += __shfl_xor(s, of);
    ss += __shfl_xor(ss, of);
  }
  const int w = tid >> 6;
  if ((tid & 63) == 0) { red[w * 2] = s; red[w * 2 + 1] = ss; }
  __syncthreads();
  s = 0.f; ss = 0.f;
#pragma unroll
  for (int q = 0; q < 8; ++q) { s += red[q * 2]; ss += red[q * 2 + 1]; }
  const float m = s * (1.0f / 512.0f);
  const float inv = rsqrtf(ss * (1.0f / 512.0f) - m * m + 1e-5f);
  o[tid] = (v - m) * inv * g[tid] + bt[tid];
  __syncthreads();
}

__device__ __forceinline__ void mlpA_body(int b, const FAParams& p,
                                          float* __restrict__ lds) {
  float* xe = lds;
  float* h1 = lds + 512;
  float* xa = lds + 1024;
  float* xt = lds + 1536;
  float* f1 = lds + 2048;
  float* red = lds + 4096;
  const int tid = threadIdx.x;

  xe[tid] = p.x_embed[(size_t)b * 512 + tid];
  __syncthreads();
  gemv_1c<1, false, false>(xe, p.attn_w1, p.attn_b1, nullptr, nullptr, h1, 512,
                           512);
  gemv_1c<3, true, false>(h1, p.attn_w2, p.attn_b2, xe, nullptr, xa, 512, 512);
  ln512t(xa, p.ln_ff_g, p.ln_ff_b, xt, red);
  {
    float a[4] = {0.f, 0.f, 0.f, 0.f};
    for (int k = 0; k < 512; ++k) {
      const float xv = xt[k];
      const float* __restrict__ Wr = p.ff_w1 + (size_t)k * 2048;
      a[0] = fmaf(xv, Wr[tid], a[0]);
      a[1] = fmaf(xv, Wr[tid + 512], a[1]);
      a[2] = fmaf(xv, Wr[tid + 1024], a[2]);
      a[3] = fmaf(xv, Wr[tid + 1536], a[3]);
    }
#pragma unroll
    for (int q = 0; q < 4; ++q)
      f1[tid + q * 512] = apply_act(a[q] + p.ff_b1[tid + q * 512], 2);
    __syncthreads();
  }
  {
    const int col = tid;
    float a0 = 0.f, a1 = 0.f, a2 = 0.f, a3 = 0.f;
    const float* __restrict__ Wp = p.ff_w2 + col;
#pragma unroll 8
    for (int k = 0; k < 2048; k += 4) {
      a0 = fmaf(f1[k + 0], Wp[(size_t)(k + 0) * 512], a0);
      a1 = fmaf(f1[k + 1], Wp[(size_t)(k + 1) * 512], a1);
      a2 = fmaf(f1[k + 2], Wp[(size_t)(k + 2) * 512], a2);
      a3 = fmaf(f1[k + 3], Wp[(size_t)(k + 3) * 512], a3);
    }
    p.xm[(size_t)b * 512 + col] =
        (a0 + a1) + (a2 + a3) + p.ff_b2[col] + xa[col];
  }
}

__global__ __launch_bounds__(512, 4) void fused_A(FAParams p) {
  extern __shared__ float ldsf[];
  const int bid = blockIdx.x;
  if (bid < 64) {
    mlpA_body(bid, p, ldsf);
  } else if (bid < 1216) {
    const int idx = bid - 64;
    const int g = idx / 9, r = idx % 9;
    if (r < 5) {
      // XCD-local permutation: this slot runs on XCD x=(g+r)&7 (round-robin,
      // 64%8==0). Give it the n-th tile of the batches {x, x+8, ..., x+56},
      // n = number of earlier gram slots on the same XCD (exactly 80 per XCD).
      const int x = (g + r) & 7;
      int n = 5 * (g >> 3);
      for (int g2 = g & ~7; g2 < g; ++g2)
        n += (((x - g2) & 7) <= 4) ? 1 : 0;
      const int gid = (x + 8 * (n / 10)) * 10 + (n % 10);
      gram_body(gid, p.X, p.G, ldsf);
    } else {
      u_body(g * 4 + (r - 5), p.Wg, p.C, p.U, ldsf, ldsf + 512 * 36);
    }
  } else {
    const int k = bid - 1216, t = threadIdx.x;
    if (t < 64) {
      float a = 0.f;
      for (int r2 = t; r2 < GR; r2 += 64) {
        float c = p.C[k * GR + r2];
        a += c * c - 2.0f * p.gbias[r2] * c;
      }
#pragma unroll
      for (int o = 32; o; o >>= 1) a += __shfl_down(a, o);
      if (t == 0) p.offs[k] = a;
    }
  }
}

// ---------------------------------------------------------------------------
// scores (verbatim)
// ---------------------------------------------------------------------------
__global__ __launch_bounds__(128) void scores_k(const float* __restrict__ G,
                                                const float* __restrict__ U,
                                                float* __restrict__ P) {
  __shared__ float Gs[64][68];
  __shared__ float Ut[20][68];

  const int tid = threadIdx.x;
  const int bsub = tid & 31, kg = tid >> 5;
  const size_t s0 = (size_t)blockIdx.x << 9;

  float acc[2][5] = {};

  for (int c0 = 0; c0 < 512; c0 += 64) {
    __syncthreads();
#pragma unroll
    for (int q = 0; q < 8; ++q) {
      int bb = q * 8 + (tid >> 4);
      float4 g4 = *(const float4*)(G + (size_t)bb * (CC * CC) + s0 + c0 +
                                   (tid & 15) * 4);
      *(float4*)&Gs[bb][(tid & 15) * 4] = g4;
    }
#pragma unroll
    for (int e = 0; e < 10; ++e) {
      int f = e * 128 + tid;
      float val = U[(s0 + c0) * KK + f];
      Ut[f % 20][f / 20] = val;
    }
    __syncthreads();
#pragma unroll
    for (int kk4 = 0; kk4 < 16; ++kk4) {
      float4 ga = *(const float4*)&Gs[bsub][kk4 * 4];
      float4 gb2 = *(const float4*)&Gs[bsub + 32][kk4 * 4];
#pragma unroll
      for (int q = 0; q < 5; ++q) {
        float4 c4 = *(const float4*)&Ut[kg * 5 + q][kk4 * 4];
        acc[0][q] = fmaf(ga.x, c4.x, acc[0][q]);
        acc[0][q] = fmaf(ga.y, c4.y, acc[0][q]);
        acc[0][q] = fmaf(ga.z, c4.z, acc[0][q]);
        acc[0][q] = fmaf(ga.w, c4.w, acc[0][q]);
        acc[1][q] = fmaf(gb2.x, c4.x, acc[1][q]);
        acc[1][q] = fmaf(gb2.y, c4.y, acc[1][q]);
        acc[1][q] = fmaf(gb2.z, c4.z, acc[1][q]);
        acc[1][q] = fmaf(gb2.w, c4.w, acc[1][q]);
      }
    }
  }
#pragma unroll
  for (int q = 0; q < 5; ++q) {
    P[(size_t)blockIdx.x * 1280 + (kg * 5 + q) * 64 + bsub] = acc[0][q];
    P[(size_t)blockIdx.x * 1280 + (kg * 5 + q) * 64 + bsub + 32] = acc[1][q];
  }
}

// ---------------------------------------------------------------------------
// mlp_row v3 (verbatim R12/R14)
// ---------------------------------------------------------------------------
struct MlpRowParams {
  const float* xm;
  const float* centers;
  const float* gm_w; const float* gm_b;
  const float* ln1_g; const float* ln1_b;
  const float* m1_w; const float* m1_b;
  const float* m2_w1; const float* m2_b1;
  const float* m2_w2; const float* m2_b2;
  const float* out_w; const float* out_b;
  const float* P; const float* offs;
  float* out;
};

template <int ACT, bool GATE, bool RES, int KS>
__device__ __forceinline__ void gemv_ks(const float* __restrict__ x,
                                        const float* __restrict__ W,
                                        const float* __restrict__ bias,
                                        const float* __restrict__ gate,
                                        const float* __restrict__ res,
                                        float* __restrict__ y, int K,
                                        float* __restrict__ part) {
  constexpr int N = 1024 / KS;
  const int tid = threadIdx.x;
  const int col = tid & (N - 1);
  const int kg = tid / N;
  const int kper = K / KS;
  const int k0 = kg * kper;
  float a0 = 0.f, a1 = 0.f, a2 = 0.f, a3 = 0.f;
  const float* __restrict__ Wp = W + (size_t)k0 * N + col;
  const float* __restrict__ xp = x + k0;
#pragma unroll 8
  for (int k = 0; k < kper; k += 4) {
    a0 = fmaf(xp[k + 0], Wp[(size_t)(k + 0) * N], a0);
    a1 = fmaf(xp[k + 1], Wp[(size_t)(k + 1) * N], a1);
    a2 = fmaf(xp[k + 2], Wp[(size_t)(k + 2) * N], a2);
    a3 = fmaf(xp[k + 3], Wp[(size_t)(k + 3) * N], a3);
  }
  part[tid] = (a0 + a1) + (a2 + a3);
  __syncthreads();
  if (tid < N) {
    float s = part[tid];
#pragma unroll
    for (int q = 1; q < KS; ++q) s += part[q * N + tid];
    s = apply_act(s + bias[tid], ACT);
    if (GATE) s *= gate[tid];
    if (RES) s += res[tid];
    y[tid] = s;
  }
  __syncthreads();
}

__device__ __forceinline__ void ln512g(const float* __restrict__ y,
                                       const float* __restrict__ g,
                                       const float* __restrict__ bt,
                                       float* __restrict__ o,
                                       float* __restrict__ red) {
  const int tid = threadIdx.x;
  if (tid < 512) {
    const float v = y[tid];
    float s = v, ss = v * v;
#pragma unroll
    for (int of = 32; of; of >>= 1) {
      s += __shfl_xor(s, of);
      ss += __shfl_xor(ss, of);
    }
    const int w = tid >> 6;
    if ((tid & 63) == 0) { red[w * 2] = s; red[w * 2 + 1] = ss; }
  }
  __syncthreads();
  if (tid < 512) {
    float s = 0.f, ss = 0.f;
#pragma unroll
    for (int q = 0; q < 8; ++q) { s += red[q * 2]; ss += red[q * 2 + 1]; }
    const float m = s * (1.0f / 512.0f);
    const float inv = rsqrtf(ss * (1.0f / 512.0f) - m * m + 1e-5f);
    o[tid] = (y[tid] - m) * inv * g[tid] + bt[tid];
  }
  __syncthreads();
}

__global__ __launch_bounds__(1024) void mlp_row(MlpRowParams p) {
  __shared__ float xt[512], xf[1024], xh[512], hh[512], h2[512], h3[256];
  __shared__ float part[1024];
  __shared__ float red[16];
  __shared__ float ps[32][20];
  __shared__ float vals[20];
  __shared__ int bestIdx;

  const int b = blockIdx.x;
  const int tid = threadIdx.x;

  {
    const int g = tid >> 5, k = tid & 31;
    if (k < 20) {
      float s = 0.f;
#pragma unroll 4
      for (int m2 = 0; m2 < 16; ++m2)
        s += p.P[(size_t)(g + 32 * m2) * 1280 + k * 64 + b];
      ps[g][k] = s;
    }
    __syncthreads();
    if (tid < 20) {
      float s = 0.f;
#pragma unroll
      for (int q = 0; q < 32; ++q) s += ps[q][tid];
      vals[tid] = p.offs[tid] - 2.0f * s;
    }
    __syncthreads();
    if (tid == 0) {
      float best = vals[0];
      int bi = 0;
      for (int k2 = 1; k2 < 20; ++k2)
        if (vals[k2] < best) { best = vals[k2]; bi = k2; }
      bestIdx = bi;
    }
    __syncthreads();
    if (tid < 512) {
      xf[tid] = p.xm[(size_t)b * 512 + tid];
      xf[512 + tid] = p.centers[(size_t)bestIdx * 512 + tid];
    }
    __syncthreads();
  }

  gemv_ks<2, false, false, 2>(xf, p.gm_w, p.gm_b, nullptr, nullptr, xh, 1024,
                              part);
  ln512g(xh, p.ln1_g, p.ln1_b, xt, red);
  gemv_ks<2, false, true, 2>(xt, p.m1_w, p.m1_b, nullptr, xh, hh, 512, part);
  gemv_ks<2, false, false, 2>(hh, p.m2_w1, p.m2_b1, nullptr, nullptr, h2, 512,
                              part);
  gemv_ks<2, false, false, 4>(h2, p.m2_w2, p.m2_b2, nullptr, nullptr, h3, 512,
                              part);
  if (tid < 10) {
    float s = p.out_b[tid];
#pragma unroll 4
    for (int k = 0; k < 256; ++k) s = fmaf(h3[k], p.out_w[k * 10 + tid], s);
    p.out[(size_t)b * 10 + tid] = s;
  }
}

// ---------------------------------------------------------------------------
extern "C" void kernel_launch(void* const* d_in, const int* in_sizes, int n_in,
                              void* d_out, int out_size, void* d_ws,
                              size_t ws_size, hipStream_t stream) {
  const float* x_embed = (const float*)d_in[0];
  const float* x_image = (const float*)d_in[1];
  const float* attn_w1 = (const float*)d_in[2];
  const float* attn_b1 = (const float*)d_in[3];
  const float* attn_w2 = (const float*)d_in[4];
  const float* attn_b2 = (const float*)d_in[5];
  const float* ln_ff_g = (const float*)d_in[6];
  const float* ln_ff_b = (const float*)d_in[7];
  const float* ff_w1 = (const float*)d_in[8];
  const float* ff_b1 = (const float*)d_in[9];
  const float* ff_w2 = (const float*)d_in[10];
  const float* ff_b2 = (const float*)d_in[11];
  const float* gram_w = (const float*)d_in[12];
  const float* gram_b = (const float*)d_in[13];
  const float* centers = (const float*)d_in[14];
  const float* gm_w = (const float*)d_in[15];
  const float* gm_b = (const float*)d_in[16];
  const float* ln1_g = (const float*)d_in[17];
  const float* ln1_b = (const float*)d_in[18];
  const float* m1_w = (const float*)d_in[19];
  const float* m1_b = (const float*)d_in[20];
  const float* m2_w1 = (const float*)d_in[21];
  const float* m2_b1 = (const float*)d_in[22];
  const float* m2_w2 = (const float*)d_in[23];
  const float* m2_b2 = (const float*)d_in[24];
  const float* out_w = (const float*)d_in[25];
  const float* out_b = (const float*)d_in[26];

  float* ws = (float*)d_ws;
  size_t off = 0;
  auto alloc = [&](size_t nelem) {
    float* p = ws + off;
    off += (nelem + 63) & ~(size_t)63;
    return p;
  };
  float* G = alloc((size_t)BB * CC * CC);   // 67 MB
  float* U = alloc((size_t)CC * CC * KK);   // 21 MB
  float* P = alloc((size_t)512 * 1280);     // 2.6 MB
  float* offs = alloc(64);
  float* xm = alloc(BB * DD);

  hipFuncSetAttribute(reinterpret_cast<const void*>(fused_A),
                      hipFuncAttributeMaxDynamicSharedMemorySize, 76800);

  FAParams fp;
  fp.X = x_image; fp.Wg = gram_w; fp.C = centers; fp.gbias = gram_b;
  fp.x_embed = x_embed;
  fp.attn_w1 = attn_w1; fp.attn_b1 = attn_b1;
  fp.attn_w2 = attn_w2; fp.attn_b2 = attn_b2;
  fp.ln_ff_g = ln_ff_g; fp.ln_ff_b = ln_ff_b;
  fp.ff_w1 = ff_w1; fp.ff_b1 = ff_b1;
  fp.ff_w2 = ff_w2; fp.ff_b2 = ff_b2;
  fp.G = G; fp.U = U; fp.offs = offs; fp.xm = xm;

  MlpRowParams mp;
  mp.xm = xm;
  mp.centers = centers;
  mp.gm_w = gm_w; mp.gm_b = gm_b;
  mp.ln1_g = ln1_g; mp.ln1_b = ln1_b;
  mp.m1_w = m1_w; mp.m1_b = m1_b;
  mp.m2_w1 = m2_w1; mp.m2_b1 = m2_b1;
  mp.m2_w2 = m2_w2; mp.m2_b2 = m2_b2;
  mp.out_w = out_w; mp.out_b = out_b;
  mp.P = P; mp.offs = offs;
  mp.out = (float*)d_out;

  fused_A<<<1236, 512, 76800, stream>>>(fp);
  scores_k<<<512, 128, 0, stream>>>(G, U, P);
  mlp_row<<<64, 1024, 0, stream>>>(mp);
}